// Round 10
// baseline (130.703 us; speedup 1.0000x reference)
//
#include <hip/hip_runtime.h>
#include <hip/hip_bf16.h>

typedef __attribute__((ext_vector_type(8))) short short8;
typedef __attribute__((ext_vector_type(4))) float f32x4;
typedef unsigned short u16;
typedef unsigned int u32;

// B=512, M=40, H=128, D=64, C=128.
// Factored algebra: out[c,d] = sum_m x0[m,d] * T_m[c,d],
//   T_m[c,d] = sum_h W[c,h,m] * xk[h,d]   (pure bf16 GEMM, K=H=128)
// Telescoped: T never zeroed; out += (s_m - s_{m+1}) * T_cum.
#define NB 512
#define NM 40
#define NH 128
#define ND 64
#define NC 128
#define KTOT 5120

__device__ __forceinline__ u16 f2bf_rne(float f) {
    u32 u = __float_as_uint(f);
    u32 r = u + 0x7FFFu + ((u >> 16) & 1u);
    return (u16)(r >> 16);
}

// pre-kernel: W fp32 [C][h*40+m] -> bf16 W3 [m][t][q][c][8], h = t*32+q*8+j.
__global__ void w3_kernel(const float* __restrict__ W, u16* __restrict__ W3) {
    __shared__ u16 kbuf[KTOT];
    const int c = blockIdx.x;
    const float* src = W + (size_t)c * KTOT;
    for (int k = threadIdx.x; k < KTOT; k += 256)
        kbuf[k] = f2bf_rne(src[k]);
    __syncthreads();
    for (int n = threadIdx.x; n < 640; n += 256) {   // n = m*16 + t*4 + q
        int m = n >> 4, t = (n >> 2) & 3, q = n & 3;
        union { short8 s8; u16 e[8]; } v;
#pragma unroll
        for (int j = 0; j < 8; ++j)
            v.e[j] = kbuf[(t * 32 + q * 8 + j) * NM + m];
        *(short8*)(W3 + ((size_t)n * 128 + c) * 8) = v.s8;
    }
}

// main: grid 512 (1 batch/block), 512 thr = 8 waves, wave = 16 rows x 64
// cols, FULL K per wave (160 t-steps) -> 4096 waves = 4 waves/SIMD (the
// latency-hiding v4-v9 lacked at 2/SIMD). Body = 1 A-load + 4 MFMA.
// B-frags (16, m-invariant) register-cached; A depth-2 pipelined from L2.
// No K-split -> no reduce epilogue; direct store.
__global__ void __launch_bounds__(512, 2) cin_main(
    const float* __restrict__ x0g, const float* __restrict__ xkg,
    const float* __restrict__ biasg, const u16* __restrict__ W3,
    float* __restrict__ out)
{
    __shared__ __align__(16) char smem[28800];
    short* xkT    = (short*)smem;              // [64][136] bf16 = 17408 B
    float* x0s    = (float*)(smem + 17408);    // [40][68]  f32  = 10880 B
    float* bias_s = (float*)(smem + 28288);    // 512 B

    const int tid = threadIdx.x;
    const int w = tid >> 6, L = tid & 63;
    const int q = L >> 4, l16 = L & 15;
    const size_t b = blockIdx.x;

    // A frag (m,t): shorts index m*16384 + t*4096 + q*1024 + c*8,
    // c = w*16 + l16 (each wave owns 16 rows exclusively)
    const u16* Ap = W3 + q * 1024 + (size_t)(w * 16 + l16) * 8;

    short8 aP[2];                    // depth-2 circular A pipeline, 1 frag/step
    auto loadAstep = [&](int u, short8* dst) {
        const size_t m = (size_t)(u >> 2);
        const int t = u & 3;
        *dst = *(const short8*)(Ap + m * 16384 + t * 4096);
    };
    loadAstep(0, &aP[0]);            // issued before prologue: latency hidden
    loadAstep(1, &aP[1]);

    // ---- prologue: xk -> bf16 xkT (transposed), x0 -> LDS, bias
    {
        const float* xp = xkg + b * (NH * ND);
        for (int i = tid; i < 2048; i += 512) {        // (h, d4)
            int h = i >> 4, d4 = (i & 15) << 2;
            float4 v = *(const float4*)(xp + h * ND + d4);
            xkT[(d4 + 0) * 136 + h] = (short)f2bf_rne(v.x);
            xkT[(d4 + 1) * 136 + h] = (short)f2bf_rne(v.y);
            xkT[(d4 + 2) * 136 + h] = (short)f2bf_rne(v.z);
            xkT[(d4 + 3) * 136 + h] = (short)f2bf_rne(v.w);
        }
        const float* x0p = x0g + b * (NM * ND);
        for (int i = tid; i < 640; i += 512) {
            int m = i >> 4, d4 = (i & 15) << 2;
            *(f32x4*)(x0s + m * 68 + d4) = *(const f32x4*)(x0p + m * ND + d4);
        }
        if (tid < NC) bias_s[tid] = biasg[tid];
    }
    __syncthreads();

    // B frag (t,n): xkT[(n*16+l16)*136 + t*32 + q*8] — cache ALL 16 in regs
    const short* Bp = xkT + (size_t)l16 * 136 + q * 8;
    short8 bR[4][4];
#pragma unroll
    for (int t = 0; t < 4; ++t)
#pragma unroll
        for (int n = 0; n < 4; ++n)
            bR[t][n] = *(const short8*)(Bp + n * (16 * 136) + t * 32);

    float s[4], sn[4];
#pragma unroll
    for (int n = 0; n < 4; ++n)
        s[n] = x0s[n * 16 + l16];            // m = 0

    f32x4 T[4] = {};        // cumulative GEMM acc (16 rows x 64 cols)
    f32x4 o[4] = {};        // scaled output acc

#pragma unroll 4
    for (int u = 0; u < 160; ++u) {          // u = m*4 + t
        const int t = u & 3;
        if (t == 0) {
            const int m = u >> 2;
#pragma unroll
            for (int n = 0; n < 4; ++n)
                sn[n] = (m < 39) ? x0s[(m + 1) * 68 + n * 16 + l16] : 0.f;
        }
        const short8 aC = aP[u & 1];
#pragma unroll
        for (int n = 0; n < 4; ++n)
            T[n] = __builtin_amdgcn_mfma_f32_16x16x32_bf16(aC, bR[t][n], T[n], 0, 0, 0);
        const int up = (u + 2 < 160) ? (u + 2) : u;   // clamped tail reload
        loadAstep(up, &aP[u & 1]);
        if (t == 3) {        // telescoped scale: out += (s_m - s_{m+1}) * T
#pragma unroll
            for (int n = 0; n < 4; ++n) {
                const float dd = s[n] - sn[n];
                o[n] += dd * T[n];
                s[n] = sn[n];
            }
        }
    }

    // ---- epilogue: direct store (wave owns its 16 rows), +bias
    float* op = out + b * (NC * ND);
#pragma unroll
    for (int n = 0; n < 4; ++n) {
        const int d = n * 16 + l16;
#pragma unroll
        for (int rr = 0; rr < 4; ++rr) {
            const int c = w * 16 + q * 4 + rr;
            op[c * ND + d] = o[n][rr] + bias_s[c];
        }
    }
}

extern "C" void kernel_launch(void* const* d_in, const int* in_sizes, int n_in,
                              void* d_out, int out_size, void* d_ws, size_t ws_size,
                              hipStream_t stream) {
    const float* x0 = (const float*)d_in[0];
    const float* xk = (const float*)d_in[1];
    const float* W  = (const float*)d_in[2];
    const float* bi = (const float*)d_in[3];
    float* out = (float*)d_out;

    u16* W3 = (u16*)d_ws;                      // 655360 shorts = 1.31 MB

    w3_kernel<<<NC, 256, 0, stream>>>(W, W3);
    cin_main<<<NB, 512, 0, stream>>>(x0, xk, bi, W3, out);
}